// Round 1
// 3129.979 us; speedup vs baseline: 2.2114x; 2.2114x over previous
//
#include <hip/hip_runtime.h>
#include <cstdint>
#include <cstddef>

#define B_    8
#define N_    2048
#define D_    1024
#define EO_   4
#define EI_   4
#define H_    4096
#define CO_   640
#define CI_   200
#define NTOK  (B_*N_)          // 16384
#define NSLOT (EO_*B_*CO_)     // 20480 outer slots
#define MP    1664             // padded rows per (eo,ei) pair = 13*128 (>= B_*CI_=1600)
#define NISLP (16*MP)          // padded inner slots
#define GP    4                // pairs per GEMM group
#define EPS_  1e-9f

typedef unsigned short u16;
typedef __attribute__((ext_vector_type(8))) short bf16x8;   // 8 bf16 in 4 VGPRs
typedef __attribute__((ext_vector_type(4))) float f32x4;
typedef __attribute__((ext_vector_type(4))) unsigned short u16x4;

// split fp32 -> bf16 hi + bf16 lo (round-to-nearest-even both).
// x ~= hi + lo with |x - hi - lo| <= ~2^-18 |x|
__device__ __forceinline__ void split2(float v, u16& h, u16& l) {
  unsigned b  = __float_as_uint(v);
  unsigned hb = (b + 0x7FFFu + ((b >> 16) & 1u)) >> 16;
  float fh = __uint_as_float(hb << 16);
  float r  = v - fh;                       // exact (Sterbenz)
  unsigned rb = __float_as_uint(r);
  unsigned lb = (rb + 0x7FFFu + ((rb >> 16) & 1u)) >> 16;
  h = (u16)hb; l = (u16)lb;
}

__device__ __forceinline__ void gload_lds16(const void* g, void* l) {
  __builtin_amdgcn_global_load_lds((const __attribute__((address_space(1))) void*)g,
                                   (__attribute__((address_space(3))) void*)l, 16, 0, 0);
}

// ---------------- K1: outer gate logits [B,N,EO] ----------------
__global__ void k_outer_logits(const float* __restrict__ x, const float* __restrict__ wgo,
                               float* __restrict__ logits) {
  int wave = (blockIdx.x * blockDim.x + threadIdx.x) >> 6;  // token id
  int lane = threadIdx.x & 63;
  const float*  xr = x + (size_t)wave * D_;
  const float4* w4 = (const float4*)wgo;   // [d] -> 4 experts
  float a0 = 0.f, a1 = 0.f, a2 = 0.f, a3 = 0.f;
#pragma unroll
  for (int i = 0; i < 16; ++i) {
    int d = i * 64 + lane;
    float xv = xr[d];
    float4 wv = w4[d];
    a0 += xv * wv.x; a1 += xv * wv.y; a2 += xv * wv.z; a3 += xv * wv.w;
  }
#pragma unroll
  for (int o = 32; o > 0; o >>= 1) {
    a0 += __shfl_xor(a0, o, 64); a1 += __shfl_xor(a1, o, 64);
    a2 += __shfl_xor(a2, o, 64); a3 += __shfl_xor(a3, o, 64);
  }
  if (lane == 0) ((float4*)logits)[wave] = make_float4(a0, a1, a2, a3);
}

// ---------------- K2: outer top-2 gating (one wave per batch) ----------------
__global__ void k_outer_gate(const float* __restrict__ logits,
                             int* __restrict__ t_idx1, int* __restrict__ t_idx2,
                             int* __restrict__ t_pos1, int* __restrict__ t_pos2,
                             float* __restrict__ t_g1, float* __restrict__ t_g2,
                             int* __restrict__ oslot_tok, float* __restrict__ oslot_gate,
                             float* __restrict__ loss_acc) {
  int b = blockIdx.x;
  int lane = threadIdx.x;             // 64 threads
  unsigned long long lmask = (1ULL << lane) - 1ULL;
  int cnt1[4] = {0, 0, 0, 0};
  float accProxy[4] = {0.f, 0.f, 0.f, 0.f};

  // ---- pass A: softmax, top2, mask_1 cumsum ----
  for (int ch = 0; ch < N_ / 64; ++ch) {
    int t = b * N_ + ch * 64 + lane;
    float4 l4 = ((const float4*)logits)[t];
    float p[4];
    {
      float m = fmaxf(fmaxf(l4.x, l4.y), fmaxf(l4.z, l4.w));
      p[0] = expf(l4.x - m); p[1] = expf(l4.y - m); p[2] = expf(l4.z - m); p[3] = expf(l4.w - m);
      float inv = 1.f / (p[0] + p[1] + p[2] + p[3]);
      p[0] *= inv; p[1] *= inv; p[2] *= inv; p[3] *= inv;
    }
    int i1 = 0; float g1 = p[0];
#pragma unroll
    for (int g = 1; g < 4; ++g) if (p[g] > g1) { g1 = p[g]; i1 = g; }
    int i2 = 0; float g2 = -1.f;
#pragma unroll
    for (int g = 0; g < 4; ++g) if (g != i1 && p[g] > g2) { g2 = p[g]; i2 = g; }
    float denom = g1 + g2 + EPS_;
    float g1n = g1 / denom, g2n = g2 / denom;
    accProxy[0] += p[0]; accProxy[1] += p[1]; accProxy[2] += p[2]; accProxy[3] += p[3];

    int pos1 = 0;
#pragma unroll
    for (int e = 0; e < 4; ++e) {
      unsigned long long mb = __ballot(i1 == e);
      if (i1 == e) pos1 = cnt1[e] + (int)__popcll(mb & lmask);
      cnt1[e] += (int)__popcll(mb);
    }
    bool kept1 = pos1 < CO_;
    t_idx1[t] = i1; t_idx2[t] = i2; t_pos1[t] = pos1;
    t_g1[t] = kept1 ? g1n : 0.f;
    t_g2[t] = g2n;  // provisional; finalized in pass B
    if (kept1) {
      int s = (i1 * B_ + b) * CO_ + pos1;
      oslot_tok[s] = t; oslot_gate[s] = g1n;
    }
  }

  // ---- loss_o contribution (pre-truncation density) ----
#pragma unroll
  for (int e = 0; e < 4; ++e) {
    float v = accProxy[e];
#pragma unroll
    for (int o = 32; o > 0; o >>= 1) v += __shfl_xor(v, o, 64);
    accProxy[e] = v;
  }
  if (lane == 0) {
    float part = 0.f;
#pragma unroll
    for (int e = 0; e < 4; ++e)
      part += (accProxy[e] / (float)N_) * ((float)cnt1[e] / (float)N_);
    atomicAdd(loss_acc, part * 16.f / (float)(B_ * EO_));
  }

  // ---- pass B: mask_2 cumsum offset by truncated mask_1 count ----
  int cnt2[4];
#pragma unroll
  for (int e = 0; e < 4; ++e) cnt2[e] = cnt1[e] < CO_ ? cnt1[e] : CO_;
  for (int ch = 0; ch < N_ / 64; ++ch) {
    int t = b * N_ + ch * 64 + lane;
    int i2 = t_idx2[t];
    int pos2 = 0;
#pragma unroll
    for (int e = 0; e < 4; ++e) {
      unsigned long long mb = __ballot(i2 == e);
      if (i2 == e) pos2 = cnt2[e] + (int)__popcll(mb & lmask);
      cnt2[e] += (int)__popcll(mb);
    }
    bool kept2 = pos2 < CO_;
    float g2n = t_g2[t];
    t_pos2[t] = pos2;
    t_g2[t] = kept2 ? g2n : 0.f;
    if (kept2) {
      int s = (i2 * B_ + b) * CO_ + pos2;
      oslot_tok[s] = t; oslot_gate[s] = g2n;
    }
  }
}

// ---------------- K3: inner gate logits per outer slot ----------------
__global__ void k_inner_logits(const float* __restrict__ x, const float* __restrict__ wgi,
                               const int* __restrict__ oslot_tok, float* __restrict__ ilogits) {
  int wave = (blockIdx.x * blockDim.x + threadIdx.x) >> 6;  // slot id [0,20480)
  int lane = threadIdx.x & 63;
  int e = wave / (B_ * CO_);
  int tok = oslot_tok[wave];
  float a0 = 0.f, a1 = 0.f, a2 = 0.f, a3 = 0.f;
  if (tok >= 0) {
    const float*  xr = x + (size_t)tok * D_;
    const float4* w4 = (const float4*)wgi + (size_t)e * D_;
#pragma unroll
    for (int i = 0; i < 16; ++i) {
      int d = i * 64 + lane;
      float xv = xr[d];
      float4 wv = w4[d];
      a0 += xv * wv.x; a1 += xv * wv.y; a2 += xv * wv.z; a3 += xv * wv.w;
    }
  }
#pragma unroll
  for (int o = 32; o > 0; o >>= 1) {
    a0 += __shfl_xor(a0, o, 64); a1 += __shfl_xor(a1, o, 64);
    a2 += __shfl_xor(a2, o, 64); a3 += __shfl_xor(a3, o, 64);
  }
  if (lane == 0) ((float4*)ilogits)[wave] = make_float4(a0, a1, a2, a3);
}

// ---------------- K4: inner top-2 gating with importance (one wave per (e,b)) ----------------
__global__ void k_inner_gate(const float* __restrict__ ilogits,
                             const int* __restrict__ oslot_tok, const float* __restrict__ oslot_gate,
                             int* __restrict__ os_f1, int* __restrict__ os_p1, float* __restrict__ os_g1,
                             int* __restrict__ os_f2, int* __restrict__ os_p2, float* __restrict__ os_g2,
                             int* __restrict__ islot_tok, float* __restrict__ islot_coef,
                             float* __restrict__ loss_acc) {
  int eb = blockIdx.x;                  // 0..31
  int e = eb >> 3, b = eb & 7;
  int base = eb * CO_;
  int lane = threadIdx.x;
  unsigned long long lmask = (1ULL << lane) - 1ULL;
  int cnt1[4] = {0, 0, 0, 0};
  float accProxy[4] = {0.f, 0.f, 0.f, 0.f};

  // ---- pass A ----
  for (int ch = 0; ch < CO_ / 64; ++ch) {
    int s = base + ch * 64 + lane;
    float go = oslot_gate[s];
    bool eq1 = (go > 0.5f);            // importance == 1.0
    float4 l4 = ((const float4*)ilogits)[s];
    float p[4];
    {
      float m = fmaxf(fmaxf(l4.x, l4.y), fmaxf(l4.z, l4.w));
      p[0] = expf(l4.x - m); p[1] = expf(l4.y - m); p[2] = expf(l4.z - m); p[3] = expf(l4.w - m);
      float inv = 1.f / (p[0] + p[1] + p[2] + p[3]);
      p[0] *= inv; p[1] *= inv; p[2] *= inv; p[3] *= inv;
    }
    int i1 = 0; float g1raw = p[0];
#pragma unroll
    for (int g = 1; g < 4; ++g) if (p[g] > g1raw) { g1raw = p[g]; i1 = g; }
    int i2; float g2raw;
    if (eq1) {
      i2 = 0; g2raw = -1.f;
#pragma unroll
      for (int g = 0; g < 4; ++g) if (g != i1 && p[g] > g2raw) { g2raw = p[g]; i2 = g; }
    } else {            // importance 0.5 (or empty): mask_1 is zero -> argmax over full gates
      i2 = i1; g2raw = g1raw;
    }
    float gate1 = eq1 ? g1raw : 0.f;
    float gate2 = g2raw;
    float denom = gate1 + gate2 + EPS_;
    float g1n = gate1 / denom, g2n = gate2 / denom;
    if (eq1) { accProxy[0] += p[0]; accProxy[1] += p[1]; accProxy[2] += p[2]; accProxy[3] += p[3]; }

    int pos1 = 0;
#pragma unroll
    for (int g = 0; g < 4; ++g) {
      bool hit = eq1 && (i1 == g);
      unsigned long long mb = __ballot(hit);
      if (hit) pos1 = cnt1[g] + (int)__popcll(mb & lmask);
      cnt1[g] += (int)__popcll(mb);
    }
    bool kept1 = eq1 && (pos1 < CI_);
    os_f1[s] = i1; os_p1[s] = pos1; os_g1[s] = kept1 ? g1n : 0.f;
    os_f2[s] = i2; os_g2[s] = g2n;  // provisional
    if (kept1) {
      int ip = (e * EI_ + i1) * MP + b * CI_ + pos1;
      islot_tok[ip]  = oslot_tok[s];
      islot_coef[ip] = go * g1n;         // outer gate * inner gate
    }
  }

  // ---- loss_i contribution ----
#pragma unroll
  for (int g = 0; g < 4; ++g) {
    float v = accProxy[g];
#pragma unroll
    for (int o = 32; o > 0; o >>= 1) v += __shfl_xor(v, o, 64);
    accProxy[g] = v;
  }
  if (lane == 0) {
    float part = 0.f;
#pragma unroll
    for (int g = 0; g < 4; ++g)
      part += (accProxy[g] / (float)CO_) * ((float)cnt1[g] / (float)CO_);
    atomicAdd(loss_acc, part * 16.f / (float)(EO_ * B_ * EI_));
  }

  // ---- pass B ----
  int cnt2[4];
#pragma unroll
  for (int g = 0; g < 4; ++g) cnt2[g] = cnt1[g] < CI_ ? cnt1[g] : CI_;
  for (int ch = 0; ch < CO_ / 64; ++ch) {
    int s = base + ch * 64 + lane;
    float go2 = oslot_gate[s];
    bool act2 = (go2 > 0.f);            // importance > 0
    int i2 = os_f2[s];
    int pos2 = 0;
#pragma unroll
    for (int g = 0; g < 4; ++g) {
      bool hit = act2 && (i2 == g);
      unsigned long long mb = __ballot(hit);
      if (hit) pos2 = cnt2[g] + (int)__popcll(mb & lmask);
      cnt2[g] += (int)__popcll(mb);
    }
    bool kept2 = act2 && (pos2 < CI_);
    float g2n = os_g2[s];
    os_p2[s] = pos2;
    os_g2[s] = kept2 ? g2n : 0.f;
    if (kept2) {
      int ip = (e * EI_ + i2) * MP + b * CI_ + pos2;
      islot_tok[ip]  = oslot_tok[s];
      islot_coef[ip] = go2 * g2n;
    }
  }
}

// ---------------- gather inner-slot rows of x -> bf16 hi/lo [GP*MP][D] ----------------
__global__ __launch_bounds__(256) void k_gather_a(const float* __restrict__ x,
                                                  const int* __restrict__ itok,
                                                  u16* __restrict__ Ah, u16* __restrict__ Al) {
  int ls = blockIdx.x;                 // [0, GP*MP)
  int tok = itok[ls];
  int t = threadIdx.x;                 // 256, one float4 each
  float4 v = make_float4(0.f, 0.f, 0.f, 0.f);
  if (tok >= 0) v = ((const float4*)(x + (size_t)tok * D_))[t];
  u16 h0, l0, h1, l1, h2, l2, h3, l3;
  split2(v.x, h0, l0); split2(v.y, h1, l1); split2(v.z, h2, l2); split2(v.w, h3, l3);
  u16x4 hv = {h0, h1, h2, h3};
  u16x4 lv = {l0, l1, l2, l3};
  *(u16x4*)(Ah + (size_t)ls * D_ + t * 4) = hv;
  *(u16x4*)(Al + (size_t)ls * D_ + t * 4) = lv;
}

// ---------------- transpose + split weights: [pair][K][N] f32 -> [pair][N][K] bf16 hi/lo ----------------
__global__ __launch_bounds__(256) void k_conv_w(const float* __restrict__ w,
                                                u16* __restrict__ wh, u16* __restrict__ wl,
                                                int K, int N) {
  __shared__ float tile[32][33];
  int pair = blockIdx.z;
  int n0 = blockIdx.x * 32, k0 = blockIdx.y * 32;
  const float* wp = w + (size_t)pair * K * N;
  int tx = threadIdx.x & 31, ty = threadIdx.x >> 5;
#pragma unroll
  for (int i = 0; i < 4; ++i) {
    int r = ty + i * 8;
    tile[r][tx] = wp[(size_t)(k0 + r) * N + n0 + tx];
  }
  __syncthreads();
  size_t obase = (size_t)pair * N * K;
#pragma unroll
  for (int i = 0; i < 4; ++i) {
    int r = ty + i * 8;                 // column within tile -> n
    u16 h, l; split2(tile[tx][r], h, l);
    size_t o = obase + (size_t)(n0 + r) * K + k0 + tx;
    wh[o] = h; wl[o] = l;
  }
}

// ---------------- MFMA GEMM core: C[128x128] += A[128xKK] * B^T[128xKK]^T, split-2 bf16 ----------------
// A: [rows][KK] bf16 (hi,lo), B: [cols][KK] bf16 (hi,lo) (i.e. transposed weights)
// LDS frag-contiguous layout: region fg holds rows [fg*16,fg*16+16) x 32 k; lane i's 16B at
// fg*1024B + i*16B = (row fg*16+(i&15), k-octet i>>4) -> ds_read_b128 per frag is 1KiB linear.
template<int KK>
__device__ __forceinline__ void gemm_core(const u16* __restrict__ Ah, const u16* __restrict__ Al,
                                          size_t arow0,
                                          const u16* __restrict__ Bh, const u16* __restrict__ Bl,
                                          size_t brow0,
                                          short* lds, f32x4 (&acc)[4][4]) {
  const int tid  = threadIdx.x;
  const int lane = tid & 63;
  const int w    = tid >> 6;           // wave 0..3
  const int wm   = w >> 1, wn = w & 1; // 64x64 quadrant per wave
  short* LAh = lds;                    // 4096 shorts each region
  short* LAl = lds + 4096;
  short* LBh = lds + 8192;
  short* LBl = lds + 12288;
  const int sr = lane & 15, sk = lane >> 4;
  const size_t aoff0 = (arow0 + (size_t)(2 * w) * 16 + sr) * KK + sk * 8;
  const size_t aoff1 = aoff0 + (size_t)16 * KK;
  const size_t boff0 = (brow0 + (size_t)(2 * w) * 16 + sr) * KK + sk * 8;
  const size_t boff1 = boff0 + (size_t)16 * KK;
  short* dAh0 = LAh + (2 * w) * 512; short* dAh1 = dAh0 + 512;
  short* dAl0 = LAl + (2 * w) * 512; short* dAl1 = dAl0 + 512;
  short* dBh0 = LBh + (2 * w) * 512; short* dBh1 = dBh0 + 512;
  short* dBl0 = LBl + (2 * w) * 512; short* dBl1 = dBl0 + 512;

  for (int k0 = 0; k0 < KK; k0 += 32) {
    gload_lds16(Ah + aoff0 + k0, dAh0);
    gload_lds16(Ah + aoff1 + k0, dAh1);
    gload_lds16(Al + aoff0 + k0, dAl0);
    gload_lds16(Al + aoff1 + k0, dAl1);
    gload_lds16(Bh + boff0 + k0, dBh0);
    gload_lds16(Bh + boff1 + k0, dBh1);
    gload_lds16(Bl + boff0 + k0, dBl0);
    gload_lds16(Bl + boff1 + k0, dBl1);
    __syncthreads();
    bf16x8 ahf[4], alf[4], bhf[4], blf[4];
#pragma unroll
    for (int f = 0; f < 4; ++f) {
      ahf[f] = *(const bf16x8*)(LAh + (wm * 4 + f) * 512 + lane * 8);
      alf[f] = *(const bf16x8*)(LAl + (wm * 4 + f) * 512 + lane * 8);
      bhf[f] = *(const bf16x8*)(LBh + (wn * 4 + f) * 512 + lane * 8);
      blf[f] = *(const bf16x8*)(LBl + (wn * 4 + f) * 512 + lane * 8);
    }
#pragma unroll
    for (int mf = 0; mf < 4; ++mf)
#pragma unroll
      for (int nf = 0; nf < 4; ++nf) {
        acc[mf][nf] = __builtin_amdgcn_mfma_f32_16x16x32_bf16(ahf[mf], bhf[nf], acc[mf][nf], 0, 0, 0);
        acc[mf][nf] = __builtin_amdgcn_mfma_f32_16x16x32_bf16(ahf[mf], blf[nf], acc[mf][nf], 0, 0, 0);
        acc[mf][nf] = __builtin_amdgcn_mfma_f32_16x16x32_bf16(alf[mf], bhf[nf], acc[mf][nf], 0, 0, 0);
      }
    __syncthreads();
  }
}

// ---------------- GEMM1: hidden = relu(A @ w1), epilogue re-splits to bf16 hi/lo ----------------
__global__ __launch_bounds__(256) void k_gemm1(const u16* __restrict__ Ah, const u16* __restrict__ Al,
                                               const u16* __restrict__ Wh, const u16* __restrict__ Wl,
                                               u16* __restrict__ hh, u16* __restrict__ hl) {
  __shared__ short lds[16384];
  f32x4 acc[4][4];
  const f32x4 z4 = {0.f, 0.f, 0.f, 0.f};
#pragma unroll
  for (int i = 0; i < 4; ++i)
#pragma unroll
    for (int j = 0; j < 4; ++j) acc[i][j] = z4;
  const int zb = blockIdx.z;
  const size_t arow0 = (size_t)zb * MP + blockIdx.x * 128;
  const size_t brow0 = (size_t)zb * H_ + blockIdx.y * 128;
  gemm_core<D_>(Ah, Al, arow0, Wh, Wl, brow0, lds, acc);

  const int lane = threadIdx.x & 63, w = threadIdx.x >> 6;
  const int wm = w >> 1, wn = w & 1;
  const int cl = lane & 15, rh = lane >> 4;   // C/D: col=lane&15, row=(lane>>4)*4+reg
  const size_t row_base = (size_t)zb * MP + blockIdx.x * 128 + wm * 64;
  const int col0 = blockIdx.y * 128 + wn * 64;
#pragma unroll
  for (int mf = 0; mf < 4; ++mf)
#pragma unroll
    for (int j = 0; j < 4; ++j) {
      size_t r = row_base + mf * 16 + rh * 4 + j;
      size_t base = r * H_ + col0;
#pragma unroll
      for (int nf = 0; nf < 4; ++nf) {
        float v = fmaxf(acc[mf][nf][j], 0.f);
        u16 h, l; split2(v, h, l);
        hh[base + nf * 16 + cl] = h;
        hl[base + nf * 16 + cl] = l;
      }
    }
}

// ---------------- GEMM2: exp_out = hidden @ w2, epilogue scatters coef*row into out ----------------
__global__ __launch_bounds__(256) void k_gemm2(const u16* __restrict__ Hh, const u16* __restrict__ Hl,
                                               const u16* __restrict__ Wh, const u16* __restrict__ Wl,
                                               const int* __restrict__ itok, const float* __restrict__ icoef,
                                               float* __restrict__ out) {
  __shared__ short lds[16384];
  f32x4 acc[4][4];
  const f32x4 z4 = {0.f, 0.f, 0.f, 0.f};
#pragma unroll
  for (int i = 0; i < 4; ++i)
#pragma unroll
    for (int j = 0; j < 4; ++j) acc[i][j] = z4;
  const int zb = blockIdx.z;
  const size_t arow0 = (size_t)zb * MP + blockIdx.x * 128;
  const size_t brow0 = (size_t)zb * D_ + blockIdx.y * 128;
  gemm_core<H_>(Hh, Hl, arow0, Wh, Wl, brow0, lds, acc);

  const int lane = threadIdx.x & 63, w = threadIdx.x >> 6;
  const int wm = w >> 1, wn = w & 1;
  const int cl = lane & 15, rh = lane >> 4;
  const int row0 = blockIdx.x * 128 + wm * 64;
  const int col0 = blockIdx.y * 128 + wn * 64;
#pragma unroll
  for (int mf = 0; mf < 4; ++mf)
#pragma unroll
    for (int j = 0; j < 4; ++j) {
      int r = row0 + mf * 16 + rh * 4 + j;
      int sp = zb * MP + r;
      int tok = itok[sp];
      if (tok < 0) continue;
      float cf = icoef[sp];
      float* ob = out + (size_t)tok * D_ + col0;
#pragma unroll
      for (int nf = 0; nf < 4; ++nf)
        atomicAdd(ob + nf * 16 + cl, cf * acc[mf][nf][j]);
    }
}

__global__ void k_loss(const float* __restrict__ loss_acc, float* __restrict__ out_loss) {
  if (threadIdx.x == 0 && blockIdx.x == 0) out_loss[0] = loss_acc[0] * 0.01f;
}

// ---------------- host ----------------
extern "C" void kernel_launch(void* const* d_in, const int* in_sizes, int n_in,
                              void* d_out, int out_size, void* d_ws, size_t ws_size,
                              hipStream_t stream) {
  const float* x   = (const float*)d_in[0];
  const float* wgo = (const float*)d_in[1];
  const float* wgi = (const float*)d_in[2];
  const float* w1  = (const float*)d_in[3];
  const float* w2  = (const float*)d_in[4];
  float* out = (float*)d_out;

  char* ws = (char*)d_ws;
  size_t off = 0;
  auto alloc = [&](size_t bytes) -> void* {
    void* p = ws + off;
    off = (off + bytes + 255) & ~(size_t)255;
    return p;
  };
  float* logits_o   = (float*)alloc((size_t)NTOK * 4 * sizeof(float));
  float* ilogits    = (float*)alloc((size_t)NSLOT * 4 * sizeof(float));
  int*   t_idx1     = (int*)alloc((size_t)NTOK * sizeof(int));
  int*   t_idx2     = (int*)alloc((size_t)NTOK * sizeof(int));
  int*   t_pos1     = (int*)alloc((size_t)NTOK * sizeof(int));
  int*   t_pos2     = (int*)alloc((size_t)NTOK * sizeof(int));
  float* t_g1       = (float*)alloc((size_t)NTOK * sizeof(float));
  float* t_g2       = (float*)alloc((size_t)NTOK * sizeof(float));
  int*   oslot_tok  = (int*)alloc((size_t)NSLOT * sizeof(int));
  float* oslot_gate = (float*)alloc((size_t)NSLOT * sizeof(float));
  int*   os_f1      = (int*)alloc((size_t)NSLOT * sizeof(int));
  int*   os_p1      = (int*)alloc((size_t)NSLOT * sizeof(int));
  float* os_g1      = (float*)alloc((size_t)NSLOT * sizeof(float));
  int*   os_f2      = (int*)alloc((size_t)NSLOT * sizeof(int));
  int*   os_p2      = (int*)alloc((size_t)NSLOT * sizeof(int));
  float* os_g2      = (float*)alloc((size_t)NSLOT * sizeof(float));
  int*   islot_tok  = (int*)alloc((size_t)NISLP * sizeof(int));
  float* islot_coef = (float*)alloc((size_t)NISLP * sizeof(float));
  float* loss_acc   = (float*)alloc(256);
  // big buffers (per-group reuse): total ws ~205 MB
  u16* Ah = (u16*)alloc((size_t)GP * MP * D_ * sizeof(u16));   // 13.6 MB
  u16* Al = (u16*)alloc((size_t)GP * MP * D_ * sizeof(u16));
  u16* Wh = (u16*)alloc((size_t)GP * H_ * D_ * sizeof(u16));   // 33.6 MB (fits w1^T or w2^T group)
  u16* Wl = (u16*)alloc((size_t)GP * H_ * D_ * sizeof(u16));
  u16* hh = (u16*)alloc((size_t)GP * MP * H_ * sizeof(u16));   // 54.5 MB
  u16* hl = (u16*)alloc((size_t)GP * MP * H_ * sizeof(u16));

  hipMemsetAsync(oslot_tok, 0xFF, (size_t)NSLOT * sizeof(int), stream);
  hipMemsetAsync(oslot_gate, 0, (size_t)NSLOT * sizeof(float), stream);
  hipMemsetAsync(islot_tok, 0xFF, (size_t)NISLP * sizeof(int), stream);
  hipMemsetAsync(islot_coef, 0, (size_t)NISLP * sizeof(float), stream);
  hipMemsetAsync(loss_acc, 0, sizeof(float), stream);
  hipMemsetAsync(out, 0, (size_t)NTOK * D_ * sizeof(float), stream);

  k_outer_logits<<<NTOK / 4, 256, 0, stream>>>(x, wgo, logits_o);
  k_outer_gate<<<B_, 64, 0, stream>>>(logits_o, t_idx1, t_idx2, t_pos1, t_pos2,
                                      t_g1, t_g2, oslot_tok, oslot_gate, loss_acc);
  k_inner_logits<<<NSLOT / 4, 256, 0, stream>>>(x, wgi, oslot_tok, ilogits);
  k_inner_gate<<<EO_ * B_, 64, 0, stream>>>(ilogits, oslot_tok, oslot_gate,
                                            os_f1, os_p1, os_g1, os_f2, os_p2, os_g2,
                                            islot_tok, islot_coef, loss_acc);
  for (int g = 0; g < 4; ++g) {
    int pair0 = g * GP;
    k_gather_a<<<GP * MP, 256, 0, stream>>>(x, islot_tok + (size_t)pair0 * MP, Ah, Al);
    k_conv_w<<<dim3(H_ / 32, D_ / 32, GP), 256, 0, stream>>>(
        w1 + (size_t)pair0 * D_ * H_, Wh, Wl, D_, H_);
    k_gemm1<<<dim3(13, H_ / 128, GP), 256, 0, stream>>>(Ah, Al, Wh, Wl, hh, hl);
    k_conv_w<<<dim3(D_ / 32, H_ / 32, GP), 256, 0, stream>>>(
        w2 + (size_t)pair0 * H_ * D_, Wh, Wl, H_, D_);
    k_gemm2<<<dim3(13, D_ / 128, GP), 256, 0, stream>>>(
        hh, hl, Wh, Wl, islot_tok + (size_t)pair0 * MP, islot_coef + (size_t)pair0 * MP, out);
  }
  k_loss<<<1, 64, 0, stream>>>(loss_acc, out + (size_t)NTOK * D_);
}

// Round 3
// 3007.113 us; speedup vs baseline: 2.3018x; 1.0409x over previous
//
#include <hip/hip_runtime.h>
#include <cstdint>
#include <cstddef>

#define B_    8
#define N_    2048
#define D_    1024
#define EO_   4
#define EI_   4
#define H_    4096
#define CO_   640
#define CI_   200
#define NTOK  (B_*N_)          // 16384
#define NSLOT (EO_*B_*CO_)     // 20480 outer slots
#define MP    1664             // padded rows per (eo,ei) pair = 13*128 (>= B_*CI_=1600)
#define NISLP (16*MP)          // padded inner slots
#define GP    4                // pairs per GEMM group
#define EPS_  1e-9f

typedef unsigned short u16;
typedef __attribute__((ext_vector_type(8))) short bf16x8;   // 8 bf16 in 4 VGPRs
typedef __attribute__((ext_vector_type(4))) float f32x4;
typedef __attribute__((ext_vector_type(4))) unsigned short u16x4;

// split fp32 -> bf16 hi + bf16 lo (round-to-nearest-even both).
// x ~= hi + lo with |x - hi - lo| <= ~2^-18 |x|
__device__ __forceinline__ void split2(float v, u16& h, u16& l) {
  unsigned b  = __float_as_uint(v);
  unsigned hb = (b + 0x7FFFu + ((b >> 16) & 1u)) >> 16;
  float fh = __uint_as_float(hb << 16);
  float r  = v - fh;                       // exact (Sterbenz)
  unsigned rb = __float_as_uint(r);
  unsigned lb = (rb + 0x7FFFu + ((rb >> 16) & 1u)) >> 16;
  h = (u16)hb; l = (u16)lb;
}

__device__ __forceinline__ void gload_lds16(const void* g, void* l) {
  __builtin_amdgcn_global_load_lds((const __attribute__((address_space(1))) void*)g,
                                   (__attribute__((address_space(3))) void*)l, 16, 0, 0);
}

// ---------------- K1: outer gate logits [B,N,EO] ----------------
__global__ void k_outer_logits(const float* __restrict__ x, const float* __restrict__ wgo,
                               float* __restrict__ logits) {
  int wave = (blockIdx.x * blockDim.x + threadIdx.x) >> 6;  // token id
  int lane = threadIdx.x & 63;
  const float*  xr = x + (size_t)wave * D_;
  const float4* w4 = (const float4*)wgo;   // [d] -> 4 experts
  float a0 = 0.f, a1 = 0.f, a2 = 0.f, a3 = 0.f;
#pragma unroll
  for (int i = 0; i < 16; ++i) {
    int d = i * 64 + lane;
    float xv = xr[d];
    float4 wv = w4[d];
    a0 += xv * wv.x; a1 += xv * wv.y; a2 += xv * wv.z; a3 += xv * wv.w;
  }
#pragma unroll
  for (int o = 32; o > 0; o >>= 1) {
    a0 += __shfl_xor(a0, o, 64); a1 += __shfl_xor(a1, o, 64);
    a2 += __shfl_xor(a2, o, 64); a3 += __shfl_xor(a3, o, 64);
  }
  if (lane == 0) ((float4*)logits)[wave] = make_float4(a0, a1, a2, a3);
}

// ---------------- K2: outer top-2 gating (one wave per batch) ----------------
__global__ void k_outer_gate(const float* __restrict__ logits,
                             int* __restrict__ t_idx1, int* __restrict__ t_idx2,
                             int* __restrict__ t_pos1, int* __restrict__ t_pos2,
                             float* __restrict__ t_g1, float* __restrict__ t_g2,
                             int* __restrict__ oslot_tok, float* __restrict__ oslot_gate,
                             float* __restrict__ loss_acc) {
  int b = blockIdx.x;
  int lane = threadIdx.x;             // 64 threads
  unsigned long long lmask = (1ULL << lane) - 1ULL;
  int cnt1[4] = {0, 0, 0, 0};
  float accProxy[4] = {0.f, 0.f, 0.f, 0.f};

  // ---- pass A: softmax, top2, mask_1 cumsum ----
  for (int ch = 0; ch < N_ / 64; ++ch) {
    int t = b * N_ + ch * 64 + lane;
    float4 l4 = ((const float4*)logits)[t];
    float p[4];
    {
      float m = fmaxf(fmaxf(l4.x, l4.y), fmaxf(l4.z, l4.w));
      p[0] = expf(l4.x - m); p[1] = expf(l4.y - m); p[2] = expf(l4.z - m); p[3] = expf(l4.w - m);
      float inv = 1.f / (p[0] + p[1] + p[2] + p[3]);
      p[0] *= inv; p[1] *= inv; p[2] *= inv; p[3] *= inv;
    }
    int i1 = 0; float g1 = p[0];
#pragma unroll
    for (int g = 1; g < 4; ++g) if (p[g] > g1) { g1 = p[g]; i1 = g; }
    int i2 = 0; float g2 = -1.f;
#pragma unroll
    for (int g = 0; g < 4; ++g) if (g != i1 && p[g] > g2) { g2 = p[g]; i2 = g; }
    float denom = g1 + g2 + EPS_;
    float g1n = g1 / denom, g2n = g2 / denom;
    accProxy[0] += p[0]; accProxy[1] += p[1]; accProxy[2] += p[2]; accProxy[3] += p[3];

    int pos1 = 0;
#pragma unroll
    for (int e = 0; e < 4; ++e) {
      unsigned long long mb = __ballot(i1 == e);
      if (i1 == e) pos1 = cnt1[e] + (int)__popcll(mb & lmask);
      cnt1[e] += (int)__popcll(mb);
    }
    bool kept1 = pos1 < CO_;
    t_idx1[t] = i1; t_idx2[t] = i2; t_pos1[t] = pos1;
    t_g1[t] = kept1 ? g1n : 0.f;
    t_g2[t] = g2n;  // provisional; finalized in pass B
    if (kept1) {
      int s = (i1 * B_ + b) * CO_ + pos1;
      oslot_tok[s] = t; oslot_gate[s] = g1n;
    }
  }

  // ---- loss_o contribution (pre-truncation density) ----
#pragma unroll
  for (int e = 0; e < 4; ++e) {
    float v = accProxy[e];
#pragma unroll
    for (int o = 32; o > 0; o >>= 1) v += __shfl_xor(v, o, 64);
    accProxy[e] = v;
  }
  if (lane == 0) {
    float part = 0.f;
#pragma unroll
    for (int e = 0; e < 4; ++e)
      part += (accProxy[e] / (float)N_) * ((float)cnt1[e] / (float)N_);
    atomicAdd(loss_acc, part * 16.f / (float)(B_ * EO_));
  }

  // ---- pass B: mask_2 cumsum offset by truncated mask_1 count ----
  int cnt2[4];
#pragma unroll
  for (int e = 0; e < 4; ++e) cnt2[e] = cnt1[e] < CO_ ? cnt1[e] : CO_;
  for (int ch = 0; ch < N_ / 64; ++ch) {
    int t = b * N_ + ch * 64 + lane;
    int i2 = t_idx2[t];
    int pos2 = 0;
#pragma unroll
    for (int e = 0; e < 4; ++e) {
      unsigned long long mb = __ballot(i2 == e);
      if (i2 == e) pos2 = cnt2[e] + (int)__popcll(mb & lmask);
      cnt2[e] += (int)__popcll(mb);
    }
    bool kept2 = pos2 < CO_;
    float g2n = t_g2[t];
    t_pos2[t] = pos2;
    t_g2[t] = kept2 ? g2n : 0.f;
    if (kept2) {
      int s = (i2 * B_ + b) * CO_ + pos2;
      oslot_tok[s] = t; oslot_gate[s] = g2n;
    }
  }
}

// ---------------- K3: inner gate logits per outer slot ----------------
__global__ void k_inner_logits(const float* __restrict__ x, const float* __restrict__ wgi,
                               const int* __restrict__ oslot_tok, float* __restrict__ ilogits) {
  int wave = (blockIdx.x * blockDim.x + threadIdx.x) >> 6;  // slot id [0,20480)
  int lane = threadIdx.x & 63;
  int e = wave / (B_ * CO_);
  int tok = oslot_tok[wave];
  float a0 = 0.f, a1 = 0.f, a2 = 0.f, a3 = 0.f;
  if (tok >= 0) {
    const float*  xr = x + (size_t)tok * D_;
    const float4* w4 = (const float4*)wgi + (size_t)e * D_;
#pragma unroll
    for (int i = 0; i < 16; ++i) {
      int d = i * 64 + lane;
      float xv = xr[d];
      float4 wv = w4[d];
      a0 += xv * wv.x; a1 += xv * wv.y; a2 += xv * wv.z; a3 += xv * wv.w;
    }
  }
#pragma unroll
  for (int o = 32; o > 0; o >>= 1) {
    a0 += __shfl_xor(a0, o, 64); a1 += __shfl_xor(a1, o, 64);
    a2 += __shfl_xor(a2, o, 64); a3 += __shfl_xor(a3, o, 64);
  }
  if (lane == 0) ((float4*)ilogits)[wave] = make_float4(a0, a1, a2, a3);
}

// ---------------- K4: inner top-2 gating with importance (one wave per (e,b)) ----------------
__global__ void k_inner_gate(const float* __restrict__ ilogits,
                             const int* __restrict__ oslot_tok, const float* __restrict__ oslot_gate,
                             int* __restrict__ os_f1, int* __restrict__ os_p1, float* __restrict__ os_g1,
                             int* __restrict__ os_f2, int* __restrict__ os_p2, float* __restrict__ os_g2,
                             int* __restrict__ islot_tok, float* __restrict__ islot_coef,
                             float* __restrict__ loss_acc) {
  int eb = blockIdx.x;                  // 0..31
  int e = eb >> 3, b = eb & 7;
  int base = eb * CO_;
  int lane = threadIdx.x;
  unsigned long long lmask = (1ULL << lane) - 1ULL;
  int cnt1[4] = {0, 0, 0, 0};
  float accProxy[4] = {0.f, 0.f, 0.f, 0.f};

  // ---- pass A ----
  for (int ch = 0; ch < CO_ / 64; ++ch) {
    int s = base + ch * 64 + lane;
    float go = oslot_gate[s];
    bool eq1 = (go > 0.5f);            // importance == 1.0
    float4 l4 = ((const float4*)ilogits)[s];
    float p[4];
    {
      float m = fmaxf(fmaxf(l4.x, l4.y), fmaxf(l4.z, l4.w));
      p[0] = expf(l4.x - m); p[1] = expf(l4.y - m); p[2] = expf(l4.z - m); p[3] = expf(l4.w - m);
      float inv = 1.f / (p[0] + p[1] + p[2] + p[3]);
      p[0] *= inv; p[1] *= inv; p[2] *= inv; p[3] *= inv;
    }
    int i1 = 0; float g1raw = p[0];
#pragma unroll
    for (int g = 1; g < 4; ++g) if (p[g] > g1raw) { g1raw = p[g]; i1 = g; }
    int i2; float g2raw;
    if (eq1) {
      i2 = 0; g2raw = -1.f;
#pragma unroll
      for (int g = 0; g < 4; ++g) if (g != i1 && p[g] > g2raw) { g2raw = p[g]; i2 = g; }
    } else {            // importance 0.5 (or empty): mask_1 is zero -> argmax over full gates
      i2 = i1; g2raw = g1raw;
    }
    float gate1 = eq1 ? g1raw : 0.f;
    float gate2 = g2raw;
    float denom = gate1 + gate2 + EPS_;
    float g1n = gate1 / denom, g2n = gate2 / denom;
    if (eq1) { accProxy[0] += p[0]; accProxy[1] += p[1]; accProxy[2] += p[2]; accProxy[3] += p[3]; }

    int pos1 = 0;
#pragma unroll
    for (int g = 0; g < 4; ++g) {
      bool hit = eq1 && (i1 == g);
      unsigned long long mb = __ballot(hit);
      if (hit) pos1 = cnt1[g] + (int)__popcll(mb & lmask);
      cnt1[g] += (int)__popcll(mb);
    }
    bool kept1 = eq1 && (pos1 < CI_);
    os_f1[s] = i1; os_p1[s] = pos1; os_g1[s] = kept1 ? g1n : 0.f;
    os_f2[s] = i2; os_g2[s] = g2n;  // provisional
    if (kept1) {
      int ip = (e * EI_ + i1) * MP + b * CI_ + pos1;
      islot_tok[ip]  = oslot_tok[s];
      islot_coef[ip] = go * g1n;         // outer gate * inner gate
    }
  }

  // ---- loss_i contribution ----
#pragma unroll
  for (int g = 0; g < 4; ++g) {
    float v = accProxy[g];
#pragma unroll
    for (int o = 32; o > 0; o >>= 1) v += __shfl_xor(v, o, 64);
    accProxy[g] = v;
  }
  if (lane == 0) {
    float part = 0.f;
#pragma unroll
    for (int g = 0; g < 4; ++g)
      part += (accProxy[g] / (float)CO_) * ((float)cnt1[g] / (float)CO_);
    atomicAdd(loss_acc, part * 16.f / (float)(EO_ * B_ * EI_));
  }

  // ---- pass B ----
  int cnt2[4];
#pragma unroll
  for (int g = 0; g < 4; ++g) cnt2[g] = cnt1[g] < CI_ ? cnt1[g] : CI_;
  for (int ch = 0; ch < CO_ / 64; ++ch) {
    int s = base + ch * 64 + lane;
    float go2 = oslot_gate[s];
    bool act2 = (go2 > 0.f);            // importance > 0
    int i2 = os_f2[s];
    int pos2 = 0;
#pragma unroll
    for (int g = 0; g < 4; ++g) {
      bool hit = act2 && (i2 == g);
      unsigned long long mb = __ballot(hit);
      if (hit) pos2 = cnt2[g] + (int)__popcll(mb & lmask);
      cnt2[g] += (int)__popcll(mb);
    }
    bool kept2 = act2 && (pos2 < CI_);
    float g2n = os_g2[s];
    os_p2[s] = pos2;
    os_g2[s] = kept2 ? g2n : 0.f;
    if (kept2) {
      int ip = (e * EI_ + i2) * MP + b * CI_ + pos2;
      islot_tok[ip]  = oslot_tok[s];
      islot_coef[ip] = go2 * g2n;
    }
  }
}

// ---------------- gather inner-slot rows of x -> bf16 hi/lo [GP*MP][D] ----------------
__global__ __launch_bounds__(256) void k_gather_a(const float* __restrict__ x,
                                                  const int* __restrict__ itok,
                                                  u16* __restrict__ Ah, u16* __restrict__ Al) {
  int ls = blockIdx.x;                 // [0, GP*MP)
  int tok = itok[ls];
  int t = threadIdx.x;                 // 256, one float4 each
  float4 v = make_float4(0.f, 0.f, 0.f, 0.f);
  if (tok >= 0) v = ((const float4*)(x + (size_t)tok * D_))[t];
  u16 h0, l0, h1, l1, h2, l2, h3, l3;
  split2(v.x, h0, l0); split2(v.y, h1, l1); split2(v.z, h2, l2); split2(v.w, h3, l3);
  u16x4 hv = {h0, h1, h2, h3};
  u16x4 lv = {l0, l1, l2, l3};
  *(u16x4*)(Ah + (size_t)ls * D_ + t * 4) = hv;
  *(u16x4*)(Al + (size_t)ls * D_ + t * 4) = lv;
}

// ---------------- transpose + split weights: [pair][K][N] f32 -> [pair][N][K] bf16 hi/lo ----------------
__global__ __launch_bounds__(256) void k_conv_w(const float* __restrict__ w,
                                                u16* __restrict__ wh, u16* __restrict__ wl,
                                                int K, int N) {
  __shared__ float tile[32][33];
  int pair = blockIdx.z;
  int n0 = blockIdx.x * 32, k0 = blockIdx.y * 32;
  const float* wp = w + (size_t)pair * K * N;
  int tx = threadIdx.x & 31, ty = threadIdx.x >> 5;
#pragma unroll
  for (int i = 0; i < 4; ++i) {
    int r = ty + i * 8;
    tile[r][tx] = wp[(size_t)(k0 + r) * N + n0 + tx];
  }
  __syncthreads();
  size_t obase = (size_t)pair * N * K;
#pragma unroll
  for (int i = 0; i < 4; ++i) {
    int r = ty + i * 8;                 // column within tile -> n
    u16 h, l; split2(tile[tx][r], h, l);
    size_t o = obase + (size_t)(n0 + r) * K + k0 + tx;
    wh[o] = h; wl[o] = l;
  }
}

// ---------------- MFMA GEMM core: C[128x128] += A[128x(kend-kbeg)] * B^T, split-2 bf16 ----------------
// A: [rows][LDK] bf16 (hi,lo), B: [cols][LDK] bf16 (hi,lo) (i.e. transposed weights)
// LDS frag-contiguous layout: region fg holds rows [fg*16,fg*16+16) x 32 k; lane i's 16B at
// fg*1024B + i*16B = (row fg*16+(i&15), k-octet i>>4) -> ds_read_b128 per frag is 1KiB linear.
template<int LDK>
__device__ __forceinline__ void gemm_core(const u16* __restrict__ Ah, const u16* __restrict__ Al,
                                          size_t arow0,
                                          const u16* __restrict__ Bh, const u16* __restrict__ Bl,
                                          size_t brow0, int kbeg, int kend,
                                          short* lds, f32x4 (&acc)[4][4]) {
  const int tid  = threadIdx.x;
  const int lane = tid & 63;
  const int w    = tid >> 6;           // wave 0..3
  const int wm   = w >> 1, wn = w & 1; // 64x64 quadrant per wave
  short* LAh = lds;                    // 4096 shorts each region
  short* LAl = lds + 4096;
  short* LBh = lds + 8192;
  short* LBl = lds + 12288;
  const int sr = lane & 15, sk = lane >> 4;
  const size_t aoff0 = (arow0 + (size_t)(2 * w) * 16 + sr) * LDK + sk * 8;
  const size_t aoff1 = aoff0 + (size_t)16 * LDK;
  const size_t boff0 = (brow0 + (size_t)(2 * w) * 16 + sr) * LDK + sk * 8;
  const size_t boff1 = boff0 + (size_t)16 * LDK;
  short* dAh0 = LAh + (2 * w) * 512; short* dAh1 = dAh0 + 512;
  short* dAl0 = LAl + (2 * w) * 512; short* dAl1 = dAl0 + 512;
  short* dBh0 = LBh + (2 * w) * 512; short* dBh1 = dBh0 + 512;
  short* dBl0 = LBl + (2 * w) * 512; short* dBl1 = dBl0 + 512;

  for (int k0 = kbeg; k0 < kend; k0 += 32) {
    gload_lds16(Ah + aoff0 + k0, dAh0);
    gload_lds16(Ah + aoff1 + k0, dAh1);
    gload_lds16(Al + aoff0 + k0, dAl0);
    gload_lds16(Al + aoff1 + k0, dAl1);
    gload_lds16(Bh + boff0 + k0, dBh0);
    gload_lds16(Bh + boff1 + k0, dBh1);
    gload_lds16(Bl + boff0 + k0, dBl0);
    gload_lds16(Bl + boff1 + k0, dBl1);
    __syncthreads();
    bf16x8 ahf[4], alf[4], bhf[4], blf[4];
#pragma unroll
    for (int f = 0; f < 4; ++f) {
      ahf[f] = *(const bf16x8*)(LAh + (wm * 4 + f) * 512 + lane * 8);
      alf[f] = *(const bf16x8*)(LAl + (wm * 4 + f) * 512 + lane * 8);
      bhf[f] = *(const bf16x8*)(LBh + (wn * 4 + f) * 512 + lane * 8);
      blf[f] = *(const bf16x8*)(LBl + (wn * 4 + f) * 512 + lane * 8);
    }
#pragma unroll
    for (int mf = 0; mf < 4; ++mf)
#pragma unroll
      for (int nf = 0; nf < 4; ++nf) {
        acc[mf][nf] = __builtin_amdgcn_mfma_f32_16x16x32_bf16(ahf[mf], bhf[nf], acc[mf][nf], 0, 0, 0);
        acc[mf][nf] = __builtin_amdgcn_mfma_f32_16x16x32_bf16(ahf[mf], blf[nf], acc[mf][nf], 0, 0, 0);
        acc[mf][nf] = __builtin_amdgcn_mfma_f32_16x16x32_bf16(alf[mf], bhf[nf], acc[mf][nf], 0, 0, 0);
      }
    __syncthreads();
  }
}

// ---------------- GEMM1: hidden = relu(A @ w1), epilogue re-splits to bf16 hi/lo ----------------
// XCD-clustered swizzle: 1664 blocks = 8 XCDs x 208; group = (pair zb, y-octant), 104 blocks,
// 2 groups per XCD -> the 8 y-tiles sharing an A-row panel co-reside in one XCD L2.
__global__ __launch_bounds__(256) void k_gemm1(const u16* __restrict__ Ah, const u16* __restrict__ Al,
                                               const u16* __restrict__ Wh, const u16* __restrict__ Wl,
                                               u16* __restrict__ hh, u16* __restrict__ hl) {
  __shared__ short lds[16384];
  int lin = blockIdx.x + 13 * (blockIdx.y + 32 * blockIdx.z);
  int xcd = lin & 7, slot = lin >> 3;            // 208 slots/XCD
  int g   = (xcd << 1) | (slot >= 104 ? 1 : 0);  // 0..15
  int idx = slot >= 104 ? slot - 104 : slot;     // 0..103
  int bx  = idx % 13;
  int by  = (g & 3) * 8 + idx / 13;              // 0..31
  int zb  = g >> 2;                              // 0..3

  f32x4 acc[4][4];
  const f32x4 z4 = {0.f, 0.f, 0.f, 0.f};
#pragma unroll
  for (int i = 0; i < 4; ++i)
#pragma unroll
    for (int j = 0; j < 4; ++j) acc[i][j] = z4;
  const size_t arow0 = (size_t)zb * MP + bx * 128;
  const size_t brow0 = (size_t)zb * H_ + by * 128;
  gemm_core<D_>(Ah, Al, arow0, Wh, Wl, brow0, 0, D_, lds, acc);

  const int lane = threadIdx.x & 63, w = threadIdx.x >> 6;
  const int wm = w >> 1, wn = w & 1;
  const int cl = lane & 15, rh = lane >> 4;   // C/D: col=lane&15, row=(lane>>4)*4+reg
  const size_t row_base = (size_t)zb * MP + bx * 128 + wm * 64;
  const int col0 = by * 128 + wn * 64;
#pragma unroll
  for (int mf = 0; mf < 4; ++mf)
#pragma unroll
    for (int j = 0; j < 4; ++j) {
      size_t r = row_base + mf * 16 + rh * 4 + j;
      size_t base = r * H_ + col0;
#pragma unroll
      for (int nf = 0; nf < 4; ++nf) {
        float v = fmaxf(acc[mf][nf][j], 0.f);
        u16 h, l; split2(v, h, l);
        hh[base + nf * 16 + cl] = h;
        hl[base + nf * 16 + cl] = l;
      }
    }
}

// ---------------- GEMM2: out += coef * (hidden @ w2), split-K x4 ----------------
// grid (13, 8, 16); in-kernel swizzle decodes (bx, by in 0..7, zb, kc) clustering each
// (zb,kc) group's 104 blocks on one XCD.
__global__ __launch_bounds__(256) void k_gemm2(const u16* __restrict__ Hh, const u16* __restrict__ Hl,
                                               const u16* __restrict__ Wh, const u16* __restrict__ Wl,
                                               const int* __restrict__ itok, const float* __restrict__ icoef,
                                               float* __restrict__ out) {
  __shared__ short lds[16384];
  int lin = blockIdx.x + 13 * (blockIdx.y + 8 * blockIdx.z);
  int xcd = lin & 7, slot = lin >> 3;            // 208 slots/XCD
  int g   = (xcd << 1) | (slot >= 104 ? 1 : 0);  // 0..15 -> (zb,kc)
  int idx = slot >= 104 ? slot - 104 : slot;     // 0..103
  int bx  = idx % 13;
  int by  = idx / 13;                            // 0..7
  int zb  = g >> 2;                              // pair-in-group 0..3
  int kc  = g & 3;                               // K-chunk 0..3

  f32x4 acc[4][4];
  const f32x4 z4 = {0.f, 0.f, 0.f, 0.f};
#pragma unroll
  for (int i = 0; i < 4; ++i)
#pragma unroll
    for (int j = 0; j < 4; ++j) acc[i][j] = z4;
  const size_t arow0 = (size_t)zb * MP + bx * 128;
  const size_t brow0 = (size_t)zb * D_ + by * 128;
  gemm_core<H_>(Hh, Hl, arow0, Wh, Wl, brow0, kc * 1024, kc * 1024 + 1024, lds, acc);

  const int lane = threadIdx.x & 63, w = threadIdx.x >> 6;
  const int wm = w >> 1, wn = w & 1;
  const int cl = lane & 15, rh = lane >> 4;
  const int row0 = bx * 128 + wm * 64;
  const int col0 = by * 128 + wn * 64;
#pragma unroll
  for (int mf = 0; mf < 4; ++mf)
#pragma unroll
    for (int j = 0; j < 4; ++j) {
      int r = row0 + mf * 16 + rh * 4 + j;
      int sp = zb * MP + r;
      int tok = itok[sp];
      if (tok < 0) continue;
      float cf = icoef[sp];
      float* ob = out + (size_t)tok * D_ + col0;
#pragma unroll
      for (int nf = 0; nf < 4; ++nf)
        atomicAdd(ob + nf * 16 + cl, cf * acc[mf][nf][j]);
    }
}

__global__ void k_loss(const float* __restrict__ loss_acc, float* __restrict__ out_loss) {
  if (threadIdx.x == 0 && blockIdx.x == 0) out_loss[0] = loss_acc[0] * 0.01f;
}

// ---------------- host ----------------
extern "C" void kernel_launch(void* const* d_in, const int* in_sizes, int n_in,
                              void* d_out, int out_size, void* d_ws, size_t ws_size,
                              hipStream_t stream) {
  const float* x   = (const float*)d_in[0];
  const float* wgo = (const float*)d_in[1];
  const float* wgi = (const float*)d_in[2];
  const float* w1  = (const float*)d_in[3];
  const float* w2  = (const float*)d_in[4];
  float* out = (float*)d_out;

  char* ws = (char*)d_ws;
  size_t off = 0;
  auto alloc = [&](size_t bytes) -> void* {
    void* p = ws + off;
    off = (off + bytes + 255) & ~(size_t)255;
    return p;
  };
  float* logits_o   = (float*)alloc((size_t)NTOK * 4 * sizeof(float));
  float* ilogits    = (float*)alloc((size_t)NSLOT * 4 * sizeof(float));
  int*   t_idx1     = (int*)alloc((size_t)NTOK * sizeof(int));
  int*   t_idx2     = (int*)alloc((size_t)NTOK * sizeof(int));
  int*   t_pos1     = (int*)alloc((size_t)NTOK * sizeof(int));
  int*   t_pos2     = (int*)alloc((size_t)NTOK * sizeof(int));
  float* t_g1       = (float*)alloc((size_t)NTOK * sizeof(float));
  float* t_g2       = (float*)alloc((size_t)NTOK * sizeof(float));
  int*   oslot_tok  = (int*)alloc((size_t)NSLOT * sizeof(int));
  float* oslot_gate = (float*)alloc((size_t)NSLOT * sizeof(float));
  int*   os_f1      = (int*)alloc((size_t)NSLOT * sizeof(int));
  int*   os_p1      = (int*)alloc((size_t)NSLOT * sizeof(int));
  float* os_g1      = (float*)alloc((size_t)NSLOT * sizeof(float));
  int*   os_f2      = (int*)alloc((size_t)NSLOT * sizeof(int));
  int*   os_p2      = (int*)alloc((size_t)NSLOT * sizeof(int));
  float* os_g2      = (float*)alloc((size_t)NSLOT * sizeof(float));
  int*   islot_tok  = (int*)alloc((size_t)NISLP * sizeof(int));
  float* islot_coef = (float*)alloc((size_t)NISLP * sizeof(float));
  float* loss_acc   = (float*)alloc(256);
  // big buffers (per-group reuse): total ws ~205 MB
  u16* Ah = (u16*)alloc((size_t)GP * MP * D_ * sizeof(u16));   // 13.6 MB
  u16* Al = (u16*)alloc((size_t)GP * MP * D_ * sizeof(u16));
  u16* Wh = (u16*)alloc((size_t)GP * H_ * D_ * sizeof(u16));   // 33.6 MB (fits w1^T or w2^T group)
  u16* Wl = (u16*)alloc((size_t)GP * H_ * D_ * sizeof(u16));
  u16* hh = (u16*)alloc((size_t)GP * MP * H_ * sizeof(u16));   // 54.5 MB
  u16* hl = (u16*)alloc((size_t)GP * MP * H_ * sizeof(u16));

  hipMemsetAsync(oslot_tok, 0xFF, (size_t)NSLOT * sizeof(int), stream);
  hipMemsetAsync(oslot_gate, 0, (size_t)NSLOT * sizeof(float), stream);
  hipMemsetAsync(islot_tok, 0xFF, (size_t)NISLP * sizeof(int), stream);
  hipMemsetAsync(islot_coef, 0, (size_t)NISLP * sizeof(float), stream);
  hipMemsetAsync(loss_acc, 0, sizeof(float), stream);
  hipMemsetAsync(out, 0, (size_t)NTOK * D_ * sizeof(float), stream);

  k_outer_logits<<<NTOK / 4, 256, 0, stream>>>(x, wgo, logits_o);
  k_outer_gate<<<B_, 64, 0, stream>>>(logits_o, t_idx1, t_idx2, t_pos1, t_pos2,
                                      t_g1, t_g2, oslot_tok, oslot_gate, loss_acc);
  k_inner_logits<<<NSLOT / 4, 256, 0, stream>>>(x, wgi, oslot_tok, ilogits);
  k_inner_gate<<<EO_ * B_, 64, 0, stream>>>(ilogits, oslot_tok, oslot_gate,
                                            os_f1, os_p1, os_g1, os_f2, os_p2, os_g2,
                                            islot_tok, islot_coef, loss_acc);
  for (int g = 0; g < 4; ++g) {
    int pair0 = g * GP;
    k_gather_a<<<GP * MP, 256, 0, stream>>>(x, islot_tok + (size_t)pair0 * MP, Ah, Al);
    k_conv_w<<<dim3(H_ / 32, D_ / 32, GP), 256, 0, stream>>>(
        w1 + (size_t)pair0 * D_ * H_, Wh, Wl, D_, H_);
    k_gemm1<<<dim3(13, H_ / 128, GP), 256, 0, stream>>>(Ah, Al, Wh, Wl, hh, hl);
    k_conv_w<<<dim3(D_ / 32, H_ / 32, GP), 256, 0, stream>>>(
        w2 + (size_t)pair0 * H_ * D_, Wh, Wl, H_, D_);
    k_gemm2<<<dim3(13, 8, 16), 256, 0, stream>>>(
        hh, hl, Wh, Wl, islot_tok + (size_t)pair0 * MP, islot_coef + (size_t)pair0 * MP, out);
  }
  k_loss<<<1, 64, 0, stream>>>(loss_acc, out + (size_t)NTOK * D_);
}